// Round 1
// baseline (339.430 us; speedup 1.0000x reference)
//
#include <hip/hip_runtime.h>
#include <math.h>

// fBM generator via generalized Schur (Toeplitz Cholesky) with banded generators.
//
// C[b] is SPD Toeplitz, first column c[k] = 0.5*((k+1)^a + (k-1)^a - 2 k^a),
// tapered by exp(-(k - tau)) for k >= tau; c[0] = 1 (so no 1/sqrt(c0) scaling).
// Displacement generators: g1 = c, g2 = (0, c1, ..). Step k emits L[:,k] = g1,
// then g1 <- Z g1 (cancels with window advance: no data motion), hyperbolic
// rotation zeroes g2[k+1]. Normalization 1/sqrt(1-r^2) is deferred to a scalar
// product p2 = prod(1-r^2) (r is scale-invariant), applied at the f32 cast.
// Taper => c[k] < 1e-25 beyond lag ~110, so generators live in a 128-entry
// sliding window: 2 f64/lane in one 64-lane wave, shifted via shuffles.
// y[i] += L[i,k]*u_s[k] accumulates in LDS (f32); cumsum epilogue in-wave.

#define TM1 1023   // T-1
#define NTH 64     // one wave per batch

__global__ __launch_bounds__(NTH, 1)
void fbm_schur_kernel(const float* __restrict__ alpha,
                      const float* __restrict__ tau,
                      const float* __restrict__ diffusion,
                      const float* __restrict__ du,
                      float* __restrict__ out)
{
    const int b = blockIdx.x;
    const int l = threadIdx.x;

    __shared__ float4 us[TM1 + 1];  // scaled noise, padded vec4
    __shared__ float4 y [TM1 + 1];  // dx accumulator

    const double a  = (double)alpha[b];
    const double tb = (double)tau[b];
    const float  sd = sqrtf(diffusion[b]);

    // stage du * sqrt(diffusion) into LDS; zero y
    const float* dub = du + (size_t)b * TM1 * 3;
    for (int k = l; k < TM1; k += NTH) {
        float4 v;
        v.x = dub[k*3 + 0] * sd;
        v.y = dub[k*3 + 1] * sd;
        v.z = dub[k*3 + 2] * sd;
        v.w = 0.f;
        us[k] = v;
        y[k]  = make_float4(0.f, 0.f, 0.f, 0.f);
    }

    // first-column covariance entries (f64), lags l and l+64
    auto cov = [&](int k) -> double {
        if (k == 0) return 1.0;
        double dk = (double)k;
        double ck = 0.5 * (pow(dk + 1.0, a) + pow(dk - 1.0, a) - 2.0 * pow(dk, a));
        if (dk >= tb) ck *= exp(tb - dk);   // exp(-(|dt| - tau))
        return ck;
    };
    double g1a = cov(l);          // window entries [l] and [l+64] of g1
    double g1b = cov(l + NTH);
    double g2a = (l == 0) ? 0.0 : g1a;   // g2 = (0, c1, c2, ...)
    double g2b = g1b;
    double p2  = 1.0;             // prod_{i<k} (1 - r_i^2)

    __syncthreads();

    for (int k = 0; k < TM1; ++k) {
        // true column k of L = g1_raw / sqrt(p2); cast to f32 (ref casts L too)
        float invs = rsqrtf((float)p2);
        float f1a = (float)g1a * invs;
        float f1b = (float)g1b * invs;
        float4 u = us[k];                 // broadcast read
        int ia = k + l;
        if (ia < TM1) {
            float4 ya = y[ia];
            ya.x += f1a * u.x; ya.y += f1a * u.y; ya.z += f1a * u.z;
            y[ia] = ya;
        }
        int ib = ia + NTH;
        if (ib < TM1) {
            float4 yb = y[ib];
            yb.x += f1b * u.x; yb.y += f1b * u.y; yb.z += f1b * u.z;
            y[ib] = yb;
        }

        // generator advance (unnormalized hyperbolic rotation)
        double num  = __shfl(g2a, 1);      // g2[k+1]
        double den  = __shfl(g1a, 0);      // (Z g1)[k+1] = g1[k]
        double g2pa = __shfl_down(g2a, 1); // shifted-window g2
        double g2pb = __shfl_down(g2b, 1);
        double wrap = __shfl(g2b, 0);
        if (l == NTH - 1) { g2pa = wrap; g2pb = 0.0; }

        double r  = num / den;
        double om = 1.0 - r * r;
        om = (om > 1e-300) ? om : 1e-300;  // PD guard
        p2 *= om;

        double t1a = g1a - r * g2pa;
        double t1b = g1b - r * g2pb;
        g2a = g2pa - r * g1a;
        g2b = g2pb - r * g1b;
        g1a = t1a;
        g1b = t1b;
    }

    __syncthreads();

    // cumsum over time (per dim) + write [zeros; x]
    float* outb = out + (size_t)b * (TM1 + 1) * 3;
    for (int d = 0; d < 3; ++d) {
        float carry = 0.f;
        for (int t = 0; t < 16; ++t) {
            int i = t * NTH + l;
            float v = (i < TM1) ? ((const float*)&y[i])[d] : 0.f;
            float sc = v;
            #pragma unroll
            for (int off = 1; off < NTH; off <<= 1) {
                float w = __shfl_up(sc, off);
                if (l >= off) sc += w;
            }
            float val = sc + carry;
            if (i < TM1) outb[(i + 1) * 3 + d] = val;
            carry = __shfl(val, NTH - 1);
        }
    }
    if (l == 0) { outb[0] = 0.f; outb[1] = 0.f; outb[2] = 0.f; }
}

extern "C" void kernel_launch(void* const* d_in, const int* in_sizes, int n_in,
                              void* d_out, int out_size, void* d_ws, size_t ws_size,
                              hipStream_t stream)
{
    const float* alpha     = (const float*)d_in[0];
    const float* tau       = (const float*)d_in[1];
    const float* diffusion = (const float*)d_in[2];
    const float* du        = (const float*)d_in[3];
    float* out = (float*)d_out;
    const int BS = in_sizes[0];

    fbm_schur_kernel<<<dim3(BS), dim3(NTH), 0, stream>>>(
        alpha, tau, diffusion, du, out);
}

// Round 2
// 230.069 us; speedup vs baseline: 1.4753x; 1.4753x over previous
//
#include <hip/hip_runtime.h>
#include <math.h>

// fBM generator via generalized Schur (Toeplitz Cholesky), f32 recursion.
//
// R1 post-mortem: 283us = 665 cyc/step, dominated by ~15 in-order DS ops/step
// (f64 shuffles + LDS RMW) with a single wave (no latency hiding) + f64 div.
// R2 changes:
//  - whole recursion in f32 (ref casts L to f32 anyway; threshold 5.16)
//  - den == p2 tracked as uniform scalar (den_{k+1}=den_k*(1-r^2)); r = num*rp,
//    rp = 1/p2 maintained by rcp+Newton -> no den shuffle, no divide
//  - num via v_readlane (VALU) instead of bpermute
//  - y accumulators lane-resident: lane l owns positions == l (mod 64);
//    column values delivered by rotating f1 (2 bpermutes); one masked LDS
//    write retires the single finished position per step (no LDS RMW)
//  - u[k] broadcast via readlane from per-chunk regs (1 LDS read / 64 steps)
// Per-step DS ops: 5 (was ~15); loop-carried chain ~30 cyc f32.

#define TM1 1023   // T-1
#define NTH 64     // one wave per batch

__device__ __forceinline__ float bperm(int byte_addr, float v) {
    return __int_as_float(__builtin_amdgcn_ds_bpermute(byte_addr, __float_as_int(v)));
}
__device__ __forceinline__ float rdlane(float v, int lane) {
    return __int_as_float(__builtin_amdgcn_readlane(__float_as_int(v), lane));
}

__global__ __launch_bounds__(NTH, 1)
void fbm_schur_kernel(const float* __restrict__ alpha,
                      const float* __restrict__ tau,
                      const float* __restrict__ diffusion,
                      const float* __restrict__ du,
                      float* __restrict__ out)
{
    const int b = blockIdx.x;
    const int l = threadIdx.x;

    __shared__ float4 us  [TM1 + 1];  // scaled noise (padded vec4)
    __shared__ float4 done[TM1 + 1];  // finished dx rows

    const double a  = (double)alpha[b];
    const double tb = (double)tau[b];
    const float  sd = sqrtf(diffusion[b]);

    // stage du * sqrt(diffusion) into LDS
    const float* dub = du + (size_t)b * TM1 * 3;
    for (int k = l; k < TM1; k += NTH) {
        float4 v;
        v.x = dub[k*3 + 0] * sd;
        v.y = dub[k*3 + 1] * sd;
        v.z = dub[k*3 + 2] * sd;
        v.w = 0.f;
        us[k] = v;
    }

    // first-column covariance (f64 init, cast to f32)
    auto cov = [&](int k) -> float {
        if (k == 0) return 1.0f;
        double dk = (double)k;
        double ck = 0.5 * (pow(dk + 1.0, a) + pow(dk - 1.0, a) - 2.0 * pow(dk, a));
        if (dk >= tb) ck *= exp(tb - dk);
        return (float)ck;
    };
    float g1a = cov(l);           // window [k..k+63] (lane j <-> pos k+j)
    float g1b = cov(l + NTH);     // window [k+64..k+127]
    float g2a = (l == 0) ? 0.f : g1a;
    float g2b = g1b;

    float rp   = 1.0f;  // 1/p2, p2 = prod(1-r^2) (== den of the rotation)
    float invs = 1.0f;  // 1/sqrt(p2) (column normalization, deferred)

    // lane-resident accumulators: lane l owns positions == l (mod 64);
    // acc_a = lower active position, acc_b = acc_a + 64
    float ax = 0.f, ay = 0.f, az = 0.f;
    float bx = 0.f, by = 0.f, bz = 0.f;

    const int addr_up = ((l + 1) & 63) << 2;   // g2 down-shift bpermute addr
    int addr_rot = l << 2;                     // f1 rotation addr: ((l-k)&63)<<2

    __syncthreads();

    for (int t = 0; t < 16; ++t) {
        float4 uc = us[t * NTH + l];           // this chunk's u, one per lane
        const int klim = (t == 15) ? (TM1 - 15 * NTH) : NTH;
        for (int k2 = 0; k2 < klim; ++k2) {
            const int k = t * NTH + k2;

            // emit column k of L (true column = g * invs)
            float f1a = g1a * invs;
            float f1b = g1b * invs;
            float ra = bperm(addr_rot, f1a);   // lane l <- window lane (l-k)&63
            float rb = bperm(addr_rot, f1b);
            addr_rot = (addr_rot - 4) & 252;

            float ux = rdlane(uc.x, k2);
            float uy = rdlane(uc.y, k2);
            float uz = rdlane(uc.z, k2);
            ax += ra * ux;  ay += ra * uy;  az += ra * uz;
            bx += rb * ux;  by += rb * uy;  bz += rb * uz;

            // retire: lane k2 just finished position k
            bool ret = (l == k2);
            if (ret) done[k] = make_float4(ax, ay, az, 0.f);
            ax = ret ? bx : ax;  ay = ret ? by : ay;  az = ret ? bz : az;
            bx = ret ? 0.f : bx; by = ret ? 0.f : by; bz = ret ? 0.f : bz;

            // reflection coefficient: r = g2[k+1] / p2  (den == p2 identity)
            float num = rdlane(g2a, 1);
            float r   = num * rp;
            float om  = fmaxf(1.0f - r * r, 1e-30f);
            float iom = __builtin_amdgcn_rcpf(om);
            iom = iom * (2.0f - om * iom);          // 1 Newton step
            rp *= iom;
            invs = __builtin_amdgcn_sqrtf(rp);      // for column k+1

            // generator advance (unnormalized hyperbolic rotation)
            float g2pa = bperm(addr_up, g2a);       // down-shift
            float g2pb = bperm(addr_up, g2b);
            float wrap = rdlane(g2b, 0);
            if (l == 63) { g2pa = wrap; g2pb = 0.f; }

            float n1a = g1a - r * g2pa;
            float n1b = g1b - r * g2pb;
            g2a = g2pa - r * g1a;
            g2b = g2pb - r * g1b;
            g1a = n1a;
            g1b = n1b;
        }
    }

    __syncthreads();

    // cumsum over time (3 dims jointly for ILP) + write [zeros; x]
    float* outb = out + (size_t)b * (TM1 + 1) * 3;
    float cx = 0.f, cy = 0.f, cz = 0.f;
    for (int t = 0; t < 16; ++t) {
        int i = t * NTH + l;
        float4 v = (i < TM1) ? done[i] : make_float4(0.f, 0.f, 0.f, 0.f);
        float sx = v.x, sy = v.y, sz = v.z;
        #pragma unroll
        for (int off = 1; off < NTH; off <<= 1) {
            float wx = __shfl_up(sx, off);
            float wy = __shfl_up(sy, off);
            float wz = __shfl_up(sz, off);
            if (l >= off) { sx += wx; sy += wy; sz += wz; }
        }
        float ox = sx + cx, oy = sy + cy, oz = sz + cz;
        if (i < TM1) {
            outb[(i + 1) * 3 + 0] = ox;
            outb[(i + 1) * 3 + 1] = oy;
            outb[(i + 1) * 3 + 2] = oz;
        }
        cx = __shfl(ox, NTH - 1);
        cy = __shfl(oy, NTH - 1);
        cz = __shfl(oz, NTH - 1);
    }
    if (l == 0) { outb[0] = 0.f; outb[1] = 0.f; outb[2] = 0.f; }
}

extern "C" void kernel_launch(void* const* d_in, const int* in_sizes, int n_in,
                              void* d_out, int out_size, void* d_ws, size_t ws_size,
                              hipStream_t stream)
{
    const float* alpha     = (const float*)d_in[0];
    const float* tau       = (const float*)d_in[1];
    const float* diffusion = (const float*)d_in[2];
    const float* du        = (const float*)d_in[3];
    float* out = (float*)d_out;
    const int BS = in_sizes[0];

    fbm_schur_kernel<<<dim3(BS), dim3(NTH), 0, stream>>>(
        alpha, tau, diffusion, du, out);
}

// Round 3
// 162.005 us; speedup vs baseline: 2.0952x; 1.4201x over previous
//
#include <hip/hip_runtime.h>
#include <math.h>

// fBM via generalized Schur (Toeplitz Cholesky), phase-split.
//
// R2 post-mortem: 405 cyc/step — the single serial wave paid issue+latency for
// emission bpermutes, u readlanes, retire writes, rcp/sqrt chain. R3: the
// serial loop keeps ONLY the generator recursion (2 bperm + 3 rdl + rcp +
// 4 FMA + col store); normalization is recovered in the parallel phase from
// the stored column itself (invs_k = rsqrt(colRaw[k][0]), since den == p2).
// Columns stored raw to LDS in 88-step chunks; all 4 waves then do the banded
// matvec y[r] += colRaw[k][r-k] * (du[k]*sqrt(D)*invs_k), then a 4-wave scan.

#define TM1   1023
#define NTH   256
#define CHUNK 88
#define NCHUNK 12   // 11*88 + 55 = 1023

__device__ __forceinline__ float bperm(int byte_addr, float v) {
    return __int_as_float(__builtin_amdgcn_ds_bpermute(byte_addr, __float_as_int(v)));
}
__device__ __forceinline__ float rdlane(float v, int lane) {
    return __int_as_float(__builtin_amdgcn_readlane(__float_as_int(v), lane));
}

__global__ __launch_bounds__(NTH, 1)
void fbm_schur_kernel(const float* __restrict__ alpha,
                      const float* __restrict__ tau,
                      const float* __restrict__ diffusion,
                      const float* __restrict__ du,
                      float* __restrict__ out)
{
    const int b   = blockIdx.x;
    const int tid = threadIdx.x;
    const int w   = tid >> 6;
    const int l   = tid & 63;

    __shared__ float  colD[CHUNK * 128];   // raw g1 columns, 45 KB
    __shared__ float4 uu[128];             // du*sd*invs per column (2 KB)
    __shared__ float  yx[1024], yy[1024], yz[1024];  // dx accumulators (12 KB)
    __shared__ float  wtot[12];            // wave totals for scan

    const float sd = sqrtf(diffusion[b]);
    const float* dub = du + (size_t)b * TM1 * 3;

    // phase 0: zero y
    for (int i = tid; i < 1024; i += NTH) { yx[i] = 0.f; yy[i] = 0.f; yz[i] = 0.f; }

    // generator init (wave 0 state; f64 covariance, cast f32)
    float g1a = 0.f, g1b = 0.f, g2a = 0.f, g2b = 0.f;
    if (tid < 64) {
        const double a  = (double)alpha[b];
        const double tb = (double)tau[b];
        auto cov = [&](int k) -> float {
            if (k == 0) return 1.0f;
            double dk = (double)k;
            double ck = 0.5 * (pow(dk + 1.0, a) + pow(dk - 1.0, a) - 2.0 * pow(dk, a));
            if (dk >= tb) ck *= exp(tb - dk);
            return (float)ck;
        };
        g1a = cov(l);
        g1b = cov(l + 64);
        g2a = (l == 0) ? 0.f : g1a;
        g2b = g1b;
    }
    const int addr_up = ((l + 1) & 63) << 2;

    float accx[5], accy[5], accz[5];  // unused slots trimmed by compiler

    for (int c = 0; c < NCHUNK; ++c) {
        const int c0 = c * CHUNK;
        const int Cc = (c == NCHUNK - 1) ? (TM1 - c0) : CHUNK;

        __syncthreads();  // protect colD/uu reuse vs previous phase 2

        // ---- phase 1: serial Schur steps (wave 0 only) ----
        if (tid < 64) {
            #pragma unroll 2
            for (int k2 = 0; k2 < Cc; ++k2) {
                colD[k2 * 128 + l]      = g1a;   // raw column k = c0+k2
                colD[k2 * 128 + 64 + l] = g1b;
                float den = rdlane(g1a, 0);      // == p2 (R1-verified identity)
                float num = rdlane(g2a, 1);
                float r   = num * __builtin_amdgcn_rcpf(den);
                float wrap = rdlane(g2b, 0);
                float g2pa = bperm(addr_up, g2a);
                float g2pb = bperm(addr_up, g2b);
                if (l == 63) { g2pa = wrap; g2pb = 0.f; }
                float n1a = fmaf(-r, g2pa, g1a);
                float n1b = fmaf(-r, g2pb, g1b);
                g2a = fmaf(-r, g1a, g2pa);
                g2b = fmaf(-r, g1b, g2pb);
                g1a = n1a; g1b = n1b;
            }
        }
        __syncthreads();  // columns visible

        // ---- phase 1.5: uu[k] = du[k]*sd*rsqrt(den_k) ----
        if (tid < Cc) {
            float invs = __frsqrt_rn(colD[tid * 128]) * sd;
            const float* dk = dub + (size_t)(c0 + tid) * 3;
            uu[tid] = make_float4(dk[0] * invs, dk[1] * invs, dk[2] * invs, 0.f);
        }
        __syncthreads();  // uu visible

        // ---- phase 2: banded matvec, row per thread ----
        const int rowsN = min(Cc + 127, TM1 - c0);
        if (tid < rowsN) {
            float ax = 0.f, ay = 0.f, az = 0.f;
            #pragma unroll 4
            for (int k2 = 0; k2 < Cc; ++k2) {
                int p = tid - k2;
                float v = colD[k2 * 128 + p];      // OOB/garbage masked below
                float4 u = uu[k2];                  // uniform broadcast read
                v = ((unsigned)p < 128u) ? v : 0.f;
                ax = fmaf(v, u.x, ax);
                ay = fmaf(v, u.y, ay);
                az = fmaf(v, u.z, az);
            }
            int r = c0 + tid;
            yx[r] += ax; yy[r] += ay; yz[r] += az;  // unique r per thread
        }
    }

    __syncthreads();

    // ---- cumsum: wave w scans rows [256w, 256w+256), then cross-wave offsets
    float cx = 0.f, cy = 0.f, cz = 0.f;
    for (int s = 0; s < 4; ++s) {
        int i = (w << 8) + (s << 6) + l;
        float sx = (i < TM1) ? yx[i] : 0.f;
        float sy = (i < TM1) ? yy[i] : 0.f;
        float sz = (i < TM1) ? yz[i] : 0.f;
        #pragma unroll
        for (int off = 1; off < 64; off <<= 1) {
            float tx = __shfl_up(sx, off);
            float ty = __shfl_up(sy, off);
            float tz = __shfl_up(sz, off);
            if (l >= off) { sx += tx; sy += ty; sz += tz; }
        }
        sx += cx; sy += cy; sz += cz;
        if (i < TM1) { yx[i] = sx; yy[i] = sy; yz[i] = sz; }
        cx = __shfl(sx, 63); cy = __shfl(sy, 63); cz = __shfl(sz, 63);
    }
    if (l == 0) { wtot[w * 3 + 0] = cx; wtot[w * 3 + 1] = cy; wtot[w * 3 + 2] = cz; }
    __syncthreads();

    float ox = 0.f, oy = 0.f, oz = 0.f;
    for (int q = 0; q < w; ++q) {
        ox += wtot[q * 3 + 0]; oy += wtot[q * 3 + 1]; oz += wtot[q * 3 + 2];
    }
    float* outb = out + (size_t)b * (TM1 + 1) * 3;
    for (int s = 0; s < 4; ++s) {
        int i = (w << 8) + (s << 6) + l;
        if (i < TM1) {
            outb[(i + 1) * 3 + 0] = yx[i] + ox;
            outb[(i + 1) * 3 + 1] = yy[i] + oy;
            outb[(i + 1) * 3 + 2] = yz[i] + oz;
        }
    }
    if (tid == 0) { outb[0] = 0.f; outb[1] = 0.f; outb[2] = 0.f; }
}

extern "C" void kernel_launch(void* const* d_in, const int* in_sizes, int n_in,
                              void* d_out, int out_size, void* d_ws, size_t ws_size,
                              hipStream_t stream)
{
    const float* alpha     = (const float*)d_in[0];
    const float* tau       = (const float*)d_in[1];
    const float* diffusion = (const float*)d_in[2];
    const float* du        = (const float*)d_in[3];
    float* out = (float*)d_out;
    const int BS = in_sizes[0];

    fbm_schur_kernel<<<dim3(BS), dim3(NTH), 0, stream>>>(
        alpha, tau, diffusion, du, out);
}

// Round 4
// 87.209 us; speedup vs baseline: 3.8921x; 1.8577x over previous
//
#include <hip/hip_runtime.h>
#include <math.h>

// fBM via generalized Schur (Toeplitz Cholesky), truncated at column convergence.
//
// R3 post-mortem: 63k LDS conflict-cycles traced to same-address float4 LDS
// broadcasts; serial phase (1023 steps x ~129cyc) still dominant.
// R4 theory: the exponential taper (tau <= 70) makes reflection coefficients
// decay like e^{-(k-tau)}; column changes ~ r^2 < 1e-40 beyond k=128. So:
//  - serial Schur: K0=128 steps only (verified R3 1-step recursion kept as-is)
//  - columns k>=128 are ONE converged vector Lc => tail is a convolution,
//    all 4 waves, 4 consecutive rows/thread with a sliding 4-register window
//    (1 ds_read_b128 per j per wave; us stored mod-4 plane-permuted so lane
//    addresses are stride-1 => no conflicts)
//  - no uniform-address b128 LDS reads anywhere (R3's conflict source);
//    uniform broadcasts via v_readlane from preloaded registers

#define TM1 1023
#define NTH 256
#define K0  128

__device__ __forceinline__ float bperm(int a, float v) {
    return __int_as_float(__builtin_amdgcn_ds_bpermute(a, __float_as_int(v)));
}
__device__ __forceinline__ float rdlane(float v, int s) {
    return __int_as_float(__builtin_amdgcn_readlane(__float_as_int(v), s));
}
// mod-4 deinterleaved slot for us storage: plane (k&3), index (k>>2)
__device__ __forceinline__ int uslot(int k) { return ((k & 3) << 8) | (k >> 2); }

__global__ __launch_bounds__(NTH, 1)
void fbm_schur_kernel(const float* __restrict__ alpha,
                      const float* __restrict__ tau,
                      const float* __restrict__ diffusion,
                      const float* __restrict__ du,
                      float* __restrict__ out)
{
    const int b   = blockIdx.x;
    const int tid = threadIdx.x;
    const int w   = tid >> 6;
    const int l   = tid & 63;

    __shared__ float  colD[K0 * 128];                 // raw head columns, 64 KB
    __shared__ float4 us4[1024];                      // du*sd, plane-permuted, 16 KB
    __shared__ float  yx[1024], yy[1024], yz[1024];   // dx accumulators, 12 KB
    __shared__ float  Lc[128];                        // converged normalized column
    __shared__ float  wtot[12];

    const float sd = sqrtf(diffusion[b]);
    const float* dub = du + (size_t)b * (TM1 * 3);

    // ---- stage du*sd into plane-permuted us4; zero y ----
    for (int e = tid; e < TM1 * 3; e += NTH) {
        int k = e / 3, d = e - 3 * k;
        ((float*)&us4[uslot(k)])[d] = dub[e] * sd;
    }
    for (int i = tid; i < 1024; i += NTH) { yx[i] = 0.f; yy[i] = 0.f; yz[i] = 0.f; }

    // ---- generator init (wave 0; f64 covariance, cast f32) ----
    float g1a = 0.f, g1b = 0.f, g2a = 0.f, g2b = 0.f;
    if (w == 0) {
        const double a  = (double)alpha[b];
        const double tb = (double)tau[b];
        auto cov = [&](int k) -> float {
            if (k == 0) return 1.0f;
            double dk = (double)k;
            double ck = 0.5 * (pow(dk + 1.0, a) + pow(dk - 1.0, a) - 2.0 * pow(dk, a));
            if (dk >= tb) ck *= exp(tb - dk);
            return (float)ck;
        };
        g1a = cov(l);
        g1b = cov(l + 64);
        g2a = (l == 0) ? 0.f : g1a;
        g2b = g1b;
    }
    __syncthreads();

    // ---- serial Schur: K0 steps, wave 0 (R3-verified recursion) ----
    if (w == 0) {
        const int addr_up = ((l + 1) & 63) << 2;
        for (int k = 0; k < K0; ++k) {
            colD[k * 128 + l]      = g1a;   // raw column k
            colD[k * 128 + 64 + l] = g1b;
            float den  = rdlane(g1a, 0);    // == p2 identity
            float num  = rdlane(g2a, 1);
            float r    = num * __builtin_amdgcn_rcpf(den);
            float wrap = rdlane(g2b, 0);
            float g2pa = bperm(addr_up, g2a);
            float g2pb = bperm(addr_up, g2b);
            if (l == 63) { g2pa = wrap; g2pb = 0.f; }
            float n1a = fmaf(-r, g2pa, g1a);
            float n1b = fmaf(-r, g2pb, g1b);
            g2a = fmaf(-r, g1a, g2pa);
            g2b = fmaf(-r, g1b, g2pb);
            g1a = n1a; g1b = n1b;
        }
        // converged column, normalized
        float sc = __frsqrt_rn(rdlane(g1a, 0));
        Lc[l]      = g1a * sc;
        Lc[64 + l] = g1b * sc;
    }
    __syncthreads();

    // ---- head matvec: columns 0..127, rows 0..255 (thread = row) ----
    {
        // premultiplied uc[k] = us[k] * rsqrt(den_k), held in regs, readlane bcast
        float4 v0 = us4[uslot(l)];
        float4 v1 = us4[uslot(64 + l)];
        float i0 = __frsqrt_rn(colD[l * 128]);
        float i1 = __frsqrt_rn(colD[(64 + l) * 128]);
        float ucx0 = v0.x * i0, ucy0 = v0.y * i0, ucz0 = v0.z * i0;
        float ucx1 = v1.x * i1, ucy1 = v1.y * i1, ucz1 = v1.z * i1;

        float ax = 0.f, ay = 0.f, az = 0.f;
        #pragma unroll 4
        for (int k2 = 0; k2 < 64; ++k2) {
            int p = tid - k2;
            float v = colD[k2 * 128 + p];            // off >= 0 always; masked below
            v = ((unsigned)p < 128u) ? v : 0.f;
            ax = fmaf(v, rdlane(ucx0, k2), ax);
            ay = fmaf(v, rdlane(ucy0, k2), ay);
            az = fmaf(v, rdlane(ucz0, k2), az);
        }
        #pragma unroll 4
        for (int k2 = 64; k2 < 128; ++k2) {
            int p = tid - k2;
            float v = colD[k2 * 128 + p];
            v = ((unsigned)p < 128u) ? v : 0.f;
            ax = fmaf(v, rdlane(ucx1, k2 - 64), ax);
            ay = fmaf(v, rdlane(ucy1, k2 - 64), ay);
            az = fmaf(v, rdlane(ucz1, k2 - 64), az);
        }
        yx[tid] = ax; yy[tid] = ay; yz[tid] = az;    // rows 0..255 (255 -> 0)
    }
    __syncthreads();

    // ---- tail: columns 128..1022 all equal Lc => convolution ----
    {
        float lca = Lc[l], lcb = Lc[64 + l];         // per-wave regs for bcast
        const int B = K0 + 4 * tid;                  // 4 consecutive rows B..B+3
        float4 q0 = us4[uslot(B + 0)];               // window us[B-j .. B+3-j]
        float4 q1 = us4[uslot(B + 1)];
        float4 q2 = us4[uslot(B + 2)];
        float4 q3 = us4[uslot(B + 3)];
        float a0x=0,a0y=0,a0z=0, a1x=0,a1y=0,a1z=0;
        float a2x=0,a2y=0,a2z=0, a3x=0,a3y=0,a3z=0;

        #pragma unroll 8
        for (int j = 0; j < 64; ++j) {
            float lc = rdlane(lca, j);
            a0x = fmaf(lc, q0.x, a0x); a0y = fmaf(lc, q0.y, a0y); a0z = fmaf(lc, q0.z, a0z);
            a1x = fmaf(lc, q1.x, a1x); a1y = fmaf(lc, q1.y, a1y); a1z = fmaf(lc, q1.z, a1z);
            a2x = fmaf(lc, q2.x, a2x); a2y = fmaf(lc, q2.y, a2y); a2z = fmaf(lc, q2.z, a2z);
            a3x = fmaf(lc, q3.x, a3x); a3y = fmaf(lc, q3.y, a3y); a3z = fmaf(lc, q3.z, a3z);
            int xi = B - j - 1;                      // slide window down by one
            float4 nv = us4[uslot(xi)];
            bool ok = (xi >= K0);                    // mask k < K0 (head's columns)
            nv.x = ok ? nv.x : 0.f; nv.y = ok ? nv.y : 0.f; nv.z = ok ? nv.z : 0.f;
            q3 = q2; q2 = q1; q1 = q0; q0 = nv;
        }
        #pragma unroll 8
        for (int j = 64; j < 128; ++j) {
            float lc = rdlane(lcb, j - 64);
            a0x = fmaf(lc, q0.x, a0x); a0y = fmaf(lc, q0.y, a0y); a0z = fmaf(lc, q0.z, a0z);
            a1x = fmaf(lc, q1.x, a1x); a1y = fmaf(lc, q1.y, a1y); a1z = fmaf(lc, q1.z, a1z);
            a2x = fmaf(lc, q2.x, a2x); a2y = fmaf(lc, q2.y, a2y); a2z = fmaf(lc, q2.z, a2z);
            a3x = fmaf(lc, q3.x, a3x); a3y = fmaf(lc, q3.y, a3y); a3z = fmaf(lc, q3.z, a3z);
            int xi = B - j - 1;
            float4 nv = us4[uslot(xi)];
            bool ok = (xi >= K0);
            nv.x = ok ? nv.x : 0.f; nv.y = ok ? nv.y : 0.f; nv.z = ok ? nv.z : 0.f;
            q3 = q2; q2 = q1; q1 = q0; q0 = nv;
        }
        if (B + 0 <= 1022) { yx[B+0] += a0x; yy[B+0] += a0y; yz[B+0] += a0z; }
        if (B + 1 <= 1022) { yx[B+1] += a1x; yy[B+1] += a1y; yz[B+1] += a1z; }
        if (B + 2 <= 1022) { yx[B+2] += a2x; yy[B+2] += a2y; yz[B+2] += a2z; }
        if (B + 3 <= 1022) { yx[B+3] += a3x; yy[B+3] += a3y; yz[B+3] += a3z; }
    }
    __syncthreads();

    // ---- cumsum (4-wave scan) + write [zeros; x] ----
    float cx = 0.f, cy = 0.f, cz = 0.f;
    for (int s = 0; s < 4; ++s) {
        int i = (w << 8) + (s << 6) + l;
        float sx = (i < TM1) ? yx[i] : 0.f;
        float sy = (i < TM1) ? yy[i] : 0.f;
        float sz = (i < TM1) ? yz[i] : 0.f;
        #pragma unroll
        for (int off = 1; off < 64; off <<= 1) {
            float tx = __shfl_up(sx, off);
            float ty = __shfl_up(sy, off);
            float tz = __shfl_up(sz, off);
            if (l >= off) { sx += tx; sy += ty; sz += tz; }
        }
        sx += cx; sy += cy; sz += cz;
        if (i < TM1) { yx[i] = sx; yy[i] = sy; yz[i] = sz; }
        cx = __shfl(sx, 63); cy = __shfl(sy, 63); cz = __shfl(sz, 63);
    }
    if (l == 0) { wtot[w * 3 + 0] = cx; wtot[w * 3 + 1] = cy; wtot[w * 3 + 2] = cz; }
    __syncthreads();

    float ox = 0.f, oy = 0.f, oz = 0.f;
    for (int q = 0; q < w; ++q) {
        ox += wtot[q * 3 + 0]; oy += wtot[q * 3 + 1]; oz += wtot[q * 3 + 2];
    }
    float* outb = out + (size_t)b * (TM1 + 1) * 3;
    for (int s = 0; s < 4; ++s) {
        int i = (w << 8) + (s << 6) + l;
        if (i < TM1) {
            outb[(i + 1) * 3 + 0] = yx[i] + ox;
            outb[(i + 1) * 3 + 1] = yy[i] + oy;
            outb[(i + 1) * 3 + 2] = yz[i] + oz;
        }
    }
    if (tid == 0) { outb[0] = 0.f; outb[1] = 0.f; outb[2] = 0.f; }
}

extern "C" void kernel_launch(void* const* d_in, const int* in_sizes, int n_in,
                              void* d_out, int out_size, void* d_ws, size_t ws_size,
                              hipStream_t stream)
{
    const float* alpha     = (const float*)d_in[0];
    const float* tau       = (const float*)d_in[1];
    const float* diffusion = (const float*)d_in[2];
    const float* du        = (const float*)d_in[3];
    float* out = (float*)d_out;
    const int BS = in_sizes[0];

    fbm_schur_kernel<<<dim3(BS), dim3(NTH), 0, stream>>>(
        alpha, tau, diffusion, du, out);
}